// Round 4
// baseline (497.963 us; speedup 1.0000x reference)
//
#include <hip/hip_runtime.h>
#include <hip/hip_bf16.h>
#include <cstdint>
#include <cstddef>

typedef __bf16 bf16_t;
typedef __bf16 bf16x8 __attribute__((ext_vector_type(8)));
typedef __bf16 bf16x4v __attribute__((ext_vector_type(4)));
typedef __bf16 bf16x2v __attribute__((ext_vector_type(2)));
typedef float f32x4 __attribute__((ext_vector_type(4)));
typedef uint32_t u32x4 __attribute__((ext_vector_type(4)));

#define DEVI static __device__ __forceinline__

// async global->LDS, 16B per lane. LDS dest must be wave-uniform base + lane*16.
DEVI void gl_lds16(const void* g, void* l) {
    __builtin_amdgcn_global_load_lds((const __attribute__((address_space(1))) void*)g,
                                     (__attribute__((address_space(3))) void*)l, 16, 0, 0);
}

DEVI float fexp2(float x) {
#if __has_builtin(__builtin_amdgcn_exp2f)
    return __builtin_amdgcn_exp2f(x);
#else
    return __expf(x * 0.6931471805599453f);
#endif
}

DEVI uint32_t pkbf16(float a, float b) {
    bf16x2v t;
    t[0] = (bf16_t)a;
    t[1] = (bf16_t)b;
    return __builtin_bit_cast(uint32_t, t);
}

// ---------------- cast fp32 -> bf16 (3 tensors in one launch) ----------------
__global__ __launch_bounds__(256) void castk(const float* __restrict__ i0, const float* __restrict__ i1,
                                             const float* __restrict__ i2, bf16_t* __restrict__ o0,
                                             bf16_t* __restrict__ o1, bf16_t* __restrict__ o2) {
    const float* in = blockIdx.y == 0 ? i0 : blockIdx.y == 1 ? i1 : i2;
    bf16_t* out = blockIdx.y == 0 ? o0 : blockIdx.y == 1 ? o1 : o2;
    size_t i = ((size_t)blockIdx.x * 256 + threadIdx.x) * 4;
    float4 v = *(const float4*)(in + i);
    bf16x4v o;
    o[0] = (bf16_t)v.x; o[1] = (bf16_t)v.y; o[2] = (bf16_t)v.z; o[3] = (bf16_t)v.w;
    *(bf16x4v*)(out + i) = o;
}

// ---------------- transpose+cast weight 1024x1024: Wt[n][k] = W[k][n] ----------------
__global__ __launch_bounds__(256) void wtrans(const float* __restrict__ W0, const float* __restrict__ W1,
                                              const float* __restrict__ W2, const float* __restrict__ W3,
                                              bf16_t* __restrict__ O0, bf16_t* __restrict__ O1,
                                              bf16_t* __restrict__ O2, bf16_t* __restrict__ O3) {
    const float* W; bf16_t* O;
    switch (blockIdx.z) {
        case 0: W = W0; O = O0; break;
        case 1: W = W1; O = O1; break;
        case 2: W = W2; O = O2; break;
        default: W = W3; O = O3; break;
    }
    __shared__ float t[32][33];
    int tx = threadIdx.x & 31, ty = threadIdx.x >> 5;   // 32x8
    int bx = blockIdx.x * 32, by = blockIdx.y * 32;     // bx: n, by: k
#pragma unroll
    for (int yy = 0; yy < 4; ++yy)
        t[ty + yy * 8][tx] = W[(size_t)(by + ty + yy * 8) * 1024 + bx + tx];
    __syncthreads();
#pragma unroll
    for (int yy = 0; yy < 4; ++yy)
        O[(size_t)(bx + ty + yy * 8) * 1024 + by + tx] = (bf16_t)t[tx][ty + yy * 8];
}

// ---------------- RoPE tables: ctab/stab [2048][32] fp32 ----------------
__global__ __launch_bounds__(256) void rope_tab(float* __restrict__ ctab, float* __restrict__ stab) {
    int idx = blockIdx.x * 256 + threadIdx.x;   // 65536 = 2048*32
    int s = idx >> 5, i = idx & 31;
    float inv = 1.0f / powf(10000.0f, (float)i * (1.0f / 32.0f));
    float f = (float)s * inv;
    ctab[idx] = cosf(f);
    stab[idx] = sinf(f);
}

// ---------------- fused QKV projection GEMM (grid.z selects Q/K/V) ----------------
// Grid (64,8,3): blockIdx.x = M-row tile (slow dim -> same-row blocks share an XCD's L2,
// so A row-tiles are fetched once per XCD, not 8x). blockIdx.y = N-col tile.
// C[8192,1024] = A[8192,1024] x Wt[1024,1024]^T; epilogue:
//   z=0/1: RoPE + scale, bf16 store to [b,h,s,d]    (Q: scale=log2e/8, K: scale=1)
//   z=2:   bf16 store transposed to Vt[b,h,d,s]
__global__ __launch_bounds__(256) void gemm_qkv(const bf16_t* __restrict__ Xq, const bf16_t* __restrict__ Xk,
                                                const bf16_t* __restrict__ Xv, const bf16_t* __restrict__ Wqt,
                                                const bf16_t* __restrict__ Wkt, const bf16_t* __restrict__ Wvt,
                                                const float* __restrict__ bqp, const float* __restrict__ bkp,
                                                const float* __restrict__ bvp, bf16_t* __restrict__ Qo,
                                                bf16_t* __restrict__ Ko, bf16_t* __restrict__ Vo,
                                                const float* __restrict__ ctab, const float* __restrict__ stab) {
    constexpr int K = 1024;
    const int z = blockIdx.z;
    const bf16_t* A  = z == 0 ? Xq : z == 1 ? Xk : Xv;
    const bf16_t* Bt = z == 0 ? Wqt : z == 1 ? Wkt : Wvt;
    const float* bias = z == 0 ? bqp : z == 1 ? bkp : bvp;
    bf16_t* O = z == 0 ? Qo : z == 1 ? Ko : Vo;
    const float scale = z == 0 ? 0.18033688011112042f : 1.0f;   // log2(e)/8 folded into Q

    __shared__ alignas(16) bf16_t As[128 * 32];
    __shared__ alignas(16) bf16_t Bs[128 * 32];
    const int tid = threadIdx.x;
    const int w = tid >> 6, lane = tid & 63, c = lane & 15, qd = lane >> 4;
    const int wm = w >> 1, wn = w & 1;
    const int m0 = blockIdx.x * 128, n0 = blockIdx.y * 128;
    f32x4 acc[4][4] = {};
    for (int kt = 0; kt < K / 32; ++kt) {
#pragma unroll
        for (int l = 0; l < 2; ++l) {
            int e = (l * 256 + tid) * 8;
            int row = e >> 5, col = e & 31;
            gl_lds16(A + (size_t)(m0 + row) * K + kt * 32 + col, (char*)As + (size_t)e * 2);
            gl_lds16(Bt + (size_t)(n0 + row) * K + kt * 32 + col, (char*)Bs + (size_t)e * 2);
        }
        __syncthreads();
        bf16x8 af[4], bfr[4];
#pragma unroll
        for (int i = 0; i < 4; ++i) af[i] = *(const bf16x8*)&As[(wm * 64 + i * 16 + c) * 32 + qd * 8];
#pragma unroll
        for (int j = 0; j < 4; ++j) bfr[j] = *(const bf16x8*)&Bs[(wn * 64 + j * 16 + c) * 32 + qd * 8];
#pragma unroll
        for (int i = 0; i < 4; ++i)
#pragma unroll
            for (int j = 0; j < 4; ++j)
                acc[i][j] = __builtin_amdgcn_mfma_f32_16x16x32_bf16(af[i], bfr[j], acc[i][j], 0, 0, 0);
        __syncthreads();
    }
    const int mb = m0 + wm * 64;
    const int nb = n0 + wn * 64;   // head-aligned (64): nb>>6 = head
    const int h = nb >> 6;
    if (z == 2) {
        // V: store transposed Vt[b,h,d,s], packing 4 consecutive s per store
#pragma unroll
        for (int i = 0; i < 4; ++i) {
            int m = mb + i * 16 + qd * 4;     // 4 consecutive s at r=0..3, same b
            int b = m >> 11, s = m & 2047;
#pragma unroll
            for (int j = 0; j < 4; ++j) {
                int d = j * 16 + c;
                float bv = bias[nb + d];
                bf16x4v v4;
#pragma unroll
                for (int r = 0; r < 4; ++r) v4[r] = (bf16_t)(acc[i][j][r] + bv);
                *(bf16x4v*)(O + ((size_t)(b * 16 + h) * 64 + d) * 2048 + s) = v4;
            }
        }
    } else {
#pragma unroll
        for (int i = 0; i < 4; ++i)
#pragma unroll
            for (int jh = 0; jh < 2; ++jh) {
                int d1 = jh * 16 + c;                 // [0,32)
                float b1 = bias[nb + d1];
                float b2 = bias[nb + d1 + 32];
#pragma unroll
                for (int r = 0; r < 4; ++r) {
                    int m = mb + i * 16 + qd * 4 + r;
                    int b = m >> 11, s = m & 2047;
                    float v1 = acc[i][jh][r] + b1;
                    float v2 = acc[i][jh + 2][r] + b2;
                    float ct = ctab[s * 32 + d1];
                    float st = stab[s * 32 + d1];
                    size_t base = ((size_t)(b * 16 + h) * 2048 + s) * 64;
                    O[base + d1]      = (bf16_t)((v1 * ct - v2 * st) * scale);
                    O[base + d1 + 32] = (bf16_t)((v2 * ct + v1 * st) * scale);
                }
            }
    }
}

// ---------------- out-proj GEMM: fp32 store [m,n] + bias. Grid (64,8), x = M-tile ----------------
__global__ __launch_bounds__(256) void gemm_out(const bf16_t* __restrict__ A, const bf16_t* __restrict__ Bt,
                                                const float* __restrict__ bias, float* __restrict__ O) {
    constexpr int K = 1024, N = 1024;
    __shared__ alignas(16) bf16_t As[128 * 32];
    __shared__ alignas(16) bf16_t Bs[128 * 32];
    const int tid = threadIdx.x;
    const int w = tid >> 6, lane = tid & 63, c = lane & 15, qd = lane >> 4;
    const int wm = w >> 1, wn = w & 1;
    const int m0 = blockIdx.x * 128, n0 = blockIdx.y * 128;
    f32x4 acc[4][4] = {};
    for (int kt = 0; kt < K / 32; ++kt) {
#pragma unroll
        for (int l = 0; l < 2; ++l) {
            int e = (l * 256 + tid) * 8;
            int row = e >> 5, col = e & 31;
            gl_lds16(A + (size_t)(m0 + row) * K + kt * 32 + col, (char*)As + (size_t)e * 2);
            gl_lds16(Bt + (size_t)(n0 + row) * K + kt * 32 + col, (char*)Bs + (size_t)e * 2);
        }
        __syncthreads();
        bf16x8 af[4], bfr[4];
#pragma unroll
        for (int i = 0; i < 4; ++i) af[i] = *(const bf16x8*)&As[(wm * 64 + i * 16 + c) * 32 + qd * 8];
#pragma unroll
        for (int j = 0; j < 4; ++j) bfr[j] = *(const bf16x8*)&Bs[(wn * 64 + j * 16 + c) * 32 + qd * 8];
#pragma unroll
        for (int i = 0; i < 4; ++i)
#pragma unroll
            for (int j = 0; j < 4; ++j)
                acc[i][j] = __builtin_amdgcn_mfma_f32_16x16x32_bf16(af[i], bfr[j], acc[i][j], 0, 0, 0);
        __syncthreads();
    }
    const int mb = m0 + wm * 64, nb = n0 + wn * 64;
#pragma unroll
    for (int i = 0; i < 4; ++i)
#pragma unroll
        for (int j = 0; j < 4; ++j) {
            int n = nb + j * 16 + c;
            float bv = bias[n];
#pragma unroll
            for (int r = 0; r < 4; ++r) {
                int m = mb + i * 16 + qd * 4 + r;
                O[(size_t)m * N + n] = acc[i][j][r] + bv;
            }
        }
}

// ---------------- flash attention v4 ----------------
// Grid (64,16): blockIdx.x = bh (slow dim -> the 16 q-blocks of one bh share an XCD's L2,
// K/V fetched ~once per XCD instead of 8x). blockIdx.y = q-tile.
// LDS 32KB (5 blocks/CU): Q staged transiently into KV buf0's region, fragments hoisted
// to registers, then the region is recycled as double-buffered K/V.
// Swapped-QK (St = K.Q^T) -> P packed bf16 in-register; PV A-frags via 8 shfl + 4 sel.
// Q pre-scaled by log2(e)/8. Q,K: [b,h,s,64] bf16. Vt: [b,h,64,s] bf16.
// 16B-chunk XOR swizzle (chunk^((row>>1)&7)) keeps all b128 reads conflict-free.
__global__ __launch_bounds__(256, 5) void attn(const bf16_t* __restrict__ Q, const bf16_t* __restrict__ K,
                                               const bf16_t* __restrict__ Vt, bf16_t* __restrict__ ctx) {
    constexpr int S = 2048;
    __shared__ alignas(16) char smem[32768];   // [buf][ K 8KB | V 8KB ] x2
    const int tid = threadIdx.x, w = tid >> 6, lane = tid & 63, c = lane & 15, qd = lane >> 4;
    const int bh = blockIdx.x, q0 = blockIdx.y * 128;
    const bf16_t* Qb = Q + (size_t)bh * S * 64 + (size_t)q0 * 64;
    const bf16_t* Kb = K + (size_t)bh * S * 64;
    const bf16_t* Vb = Vt + (size_t)bh * 64 * S;
    // ---- stage Q (16KB) into smem[0..16K), read fragments, then recycle the region ----
#pragma unroll
    for (int l = 0; l < 4; ++l) {
        int slot = l * 256 + tid;           // 16B slots
        int row = slot >> 3, ch = slot & 7;
        int sch = ch ^ ((row >> 1) & 7);
        gl_lds16(Qb + (size_t)row * 64 + sch * 8, smem + (size_t)slot * 16);
    }
    __syncthreads();
    const int rch = (c >> 1) & 7;                   // read-side swizzle mask
    bf16x8 qf[2][2];
    {
        const bf16_t* Qs = (const bf16_t*)smem;
#pragma unroll
        for (int kk = 0; kk < 2; ++kk) {
            const int ch = (4 * kk + qd) ^ rch;
#pragma unroll
            for (int i = 0; i < 2; ++i)
                qf[kk][i] = *(const bf16x8*)&Qs[(w * 32 + i * 16 + c) * 64 + ch * 8];
        }
    }
    __syncthreads();                                // all waves done reading Q
    auto stageKV = [&](int kt, int buf) {
        const int s0 = kt * 64;
        char* kbase = smem + buf * 16384;
        char* vbase = kbase + 8192;
#pragma unroll
        for (int l = 0; l < 2; ++l) {
            int slot = l * 256 + tid;
            int row = slot >> 3, ch = slot & 7;
            int sch = ch ^ ((row >> 1) & 7);
            gl_lds16(Kb + (size_t)(s0 + row) * 64 + sch * 8, kbase + (size_t)slot * 16);
            gl_lds16(Vb + (size_t)row * S + s0 + sch * 8, vbase + (size_t)slot * 16);
        }
    };
    stageKV(0, 0);
    __syncthreads();                                // tile 0 staged
    const int srcA = c + ((lane >> 4) & 1) * 32;    // (c, (qd&1)*2)
    const int srcB = srcA + 16;                     // (c, (qd&1)*2+1)
    const bool hisel = (qd >> 1) & 1;               // strip select: j = 2*kk + (qd>>1)
    f32x4 acc_o[2][4] = {};
    float ls[2] = {0.f, 0.f};
    const f32x4 Z = {0.f, 0.f, 0.f, 0.f};
    for (int kt = 0; kt < S / 64; ++kt) {
        const int cur = kt & 1;
        if (kt + 1 < S / 64) stageKV(kt + 1, cur ^ 1);
        const bf16_t* KsC = (const bf16_t*)(smem + cur * 16384);
        const bf16_t* VsC = (const bf16_t*)(smem + cur * 16384 + 8192);
        // St = K.Q^T : lane holds St[s=j*16+qd*4+r][q=i*16+c]
        f32x4 sc[4][2];
#pragma unroll
        for (int kk = 0; kk < 2; ++kk) {
            const int ch = (4 * kk + qd) ^ rch;
            bf16x8 kf[4];
#pragma unroll
            for (int j = 0; j < 4; ++j) kf[j] = *(const bf16x8*)&KsC[(j * 16 + c) * 64 + ch * 8];
#pragma unroll
            for (int j = 0; j < 4; ++j)
#pragma unroll
                for (int i = 0; i < 2; ++i)
                    sc[j][i] = __builtin_amdgcn_mfma_f32_16x16x32_bf16(kf[j], qf[kk][i],
                                                                       kk == 0 ? Z : sc[j][i], 0, 0, 0);
        }
        // p = 2^sc; row-sum per q (lane's q = i*16+c); pack pairs (s, s+1) -> u32
        uint32_t pku[4][2][2];
#pragma unroll
        for (int j = 0; j < 4; ++j)
#pragma unroll
            for (int i = 0; i < 2; ++i) {
                float p0 = fexp2(sc[j][i][0]), p1 = fexp2(sc[j][i][1]);
                float p2 = fexp2(sc[j][i][2]), p3 = fexp2(sc[j][i][3]);
                ls[i] += (p0 + p1) + (p2 + p3);
                pku[j][i][0] = pkbf16(p0, p1);
                pku[j][i][1] = pkbf16(p2, p3);
            }
        // O += P.V : A-frag built cross-lane, B-frag from Vts rows (d-major)
#pragma unroll
        for (int kk = 0; kk < 2; ++kk) {
            const int ch = (4 * kk + qd) ^ rch;
            bf16x8 vf[4];
#pragma unroll
            for (int j = 0; j < 4; ++j) vf[j] = *(const bf16x8*)&VsC[(j * 16 + c) * 64 + ch * 8];
#pragma unroll
            for (int i = 0; i < 2; ++i) {
                uint32_t a0, a1, a2, a3;
                {
                    uint32_t lo = __shfl(pku[2 * kk][i][0], srcA);
                    uint32_t hi = __shfl(pku[2 * kk + 1][i][0], srcA);
                    a0 = hisel ? hi : lo;
                    lo = __shfl(pku[2 * kk][i][1], srcA);
                    hi = __shfl(pku[2 * kk + 1][i][1], srcA);
                    a1 = hisel ? hi : lo;
                    lo = __shfl(pku[2 * kk][i][0], srcB);
                    hi = __shfl(pku[2 * kk + 1][i][0], srcB);
                    a2 = hisel ? hi : lo;
                    lo = __shfl(pku[2 * kk][i][1], srcB);
                    hi = __shfl(pku[2 * kk + 1][i][1], srcB);
                    a3 = hisel ? hi : lo;
                }
                u32x4 av = {a0, a1, a2, a3};
                bf16x8 af = __builtin_bit_cast(bf16x8, av);
#pragma unroll
                for (int j = 0; j < 4; ++j)
                    acc_o[i][j] = __builtin_amdgcn_mfma_f32_16x16x32_bf16(af, vf[j], acc_o[i][j], 0, 0, 0);
            }
        }
        __syncthreads();
    }
    // complete l over qd groups, redistribute inverse to C-layout rows
    float linv[2][4];
#pragma unroll
    for (int i = 0; i < 2; ++i) {
        float v = ls[i];
        v += __shfl_xor(v, 16);
        v += __shfl_xor(v, 32);
        float vinv = 1.0f / v;
#pragma unroll
        for (int r = 0; r < 4; ++r)
            linv[i][r] = __shfl(vinv, qd * 20 + r);   // lane (qd*16 + qd*4 + r): holds l[q=i*16+qd*4+r]
    }
    const int b = bh >> 4, h = bh & 15;
#pragma unroll
    for (int i = 0; i < 2; ++i)
#pragma unroll
        for (int j = 0; j < 4; ++j)
#pragma unroll
            for (int r = 0; r < 4; ++r) {
                int qrow = q0 + w * 32 + i * 16 + qd * 4 + r;
                float o = acc_o[i][j][r] * linv[i][r];
                ctx[((size_t)(b * 2048 + qrow)) * 1024 + (size_t)h * 64 + j * 16 + c] = (bf16_t)o;
            }
}

extern "C" void kernel_launch(void* const* d_in, const int* in_sizes, int n_in,
                              void* d_out, int out_size, void* d_ws, size_t ws_size,
                              hipStream_t stream) {
    (void)in_sizes; (void)n_in; (void)out_size; (void)ws_size;
    const float* query = (const float*)d_in[0];
    const float* key   = (const float*)d_in[1];
    const float* value = (const float*)d_in[2];
    const float* Wq = (const float*)d_in[3];
    const float* bq = (const float*)d_in[4];
    const float* Wk = (const float*)d_in[5];
    const float* bk = (const float*)d_in[6];
    const float* Wv = (const float*)d_in[7];
    const float* bv = (const float*)d_in[8];
    const float* Wo = (const float*)d_in[9];
    const float* bo = (const float*)d_in[10];

    const size_t SZ = (size_t)8192 * 1024;
    bf16_t* Xq = (bf16_t*)d_ws;
    bf16_t* Xk = Xq + SZ;
    bf16_t* Xv = Xk + SZ;
    bf16_t* Qb = Xv + SZ;
    bf16_t* Kb = Qb + SZ;
    bf16_t* Vtb = Kb + SZ;          // own buffer: fused QKV gemm runs Q/K/V concurrently
    bf16_t* Wqt = Vtb + SZ;
    bf16_t* Wkt = Wqt + 1024 * 1024;
    bf16_t* Wvt = Wkt + 1024 * 1024;
    bf16_t* Wot = Wvt + 1024 * 1024;
    float* ctab = (float*)(Wot + 1024 * 1024);
    float* stab = ctab + 2048 * 32;
    bf16_t* CT = Xq;                // alias: Xq dead after projection GEMM

    castk<<<dim3(8192, 3), 256, 0, stream>>>(query, key, value, Xq, Xk, Xv);
    wtrans<<<dim3(32, 32, 4), 256, 0, stream>>>(Wq, Wk, Wv, Wo, Wqt, Wkt, Wvt, Wot);
    rope_tab<<<256, 256, 0, stream>>>(ctab, stab);
    gemm_qkv<<<dim3(64, 8, 3), 256, 0, stream>>>(Xq, Xk, Xv, Wqt, Wkt, Wvt, bq, bk, bv,
                                                 Qb, Kb, Vtb, ctab, stab);
    attn<<<dim3(64, 16), 256, 0, stream>>>(Qb, Kb, Vtb, CT);
    gemm_out<<<dim3(64, 8), 256, 0, stream>>>(CT, Wot, bo, (float*)d_out);
}

// Round 5
// 392.079 us; speedup vs baseline: 1.2701x; 1.2701x over previous
//
#include <hip/hip_runtime.h>
#include <hip/hip_bf16.h>
#include <cstdint>
#include <cstddef>

typedef __bf16 bf16_t;
typedef __bf16 bf16x8 __attribute__((ext_vector_type(8)));
typedef __bf16 bf16x4v __attribute__((ext_vector_type(4)));
typedef __bf16 bf16x2v __attribute__((ext_vector_type(2)));
typedef float f32x4 __attribute__((ext_vector_type(4)));
typedef uint32_t u32x4 __attribute__((ext_vector_type(4)));

#define DEVI static __device__ __forceinline__

// async global->LDS, 16B per lane. LDS dest must be wave-uniform base + lane*16.
DEVI void gl_lds16(const void* g, void* l) {
    __builtin_amdgcn_global_load_lds((const __attribute__((address_space(1))) void*)g,
                                     (__attribute__((address_space(3))) void*)l, 16, 0, 0);
}

DEVI float fexp2(float x) {
#if __has_builtin(__builtin_amdgcn_exp2f)
    return __builtin_amdgcn_exp2f(x);
#else
    return __expf(x * 0.6931471805599453f);
#endif
}

DEVI uint32_t pkbf16(float a, float b) {
    bf16x2v t;
    t[0] = (bf16_t)a;
    t[1] = (bf16_t)b;
    return __builtin_bit_cast(uint32_t, t);
}

// ---------------- cast fp32 -> bf16 (3 tensors in one launch) ----------------
__global__ __launch_bounds__(256) void castk(const float* __restrict__ i0, const float* __restrict__ i1,
                                             const float* __restrict__ i2, bf16_t* __restrict__ o0,
                                             bf16_t* __restrict__ o1, bf16_t* __restrict__ o2) {
    const float* in = blockIdx.y == 0 ? i0 : blockIdx.y == 1 ? i1 : i2;
    bf16_t* out = blockIdx.y == 0 ? o0 : blockIdx.y == 1 ? o1 : o2;
    size_t i = ((size_t)blockIdx.x * 256 + threadIdx.x) * 4;
    float4 v = *(const float4*)(in + i);
    bf16x4v o;
    o[0] = (bf16_t)v.x; o[1] = (bf16_t)v.y; o[2] = (bf16_t)v.z; o[3] = (bf16_t)v.w;
    *(bf16x4v*)(out + i) = o;
}

// ---------------- transpose+cast weight 1024x1024: Wt[n][k] = W[k][n] ----------------
__global__ __launch_bounds__(256) void wtrans(const float* __restrict__ W0, const float* __restrict__ W1,
                                              const float* __restrict__ W2, const float* __restrict__ W3,
                                              bf16_t* __restrict__ O0, bf16_t* __restrict__ O1,
                                              bf16_t* __restrict__ O2, bf16_t* __restrict__ O3) {
    const float* W; bf16_t* O;
    switch (blockIdx.z) {
        case 0: W = W0; O = O0; break;
        case 1: W = W1; O = O1; break;
        case 2: W = W2; O = O2; break;
        default: W = W3; O = O3; break;
    }
    __shared__ float t[32][33];
    int tx = threadIdx.x & 31, ty = threadIdx.x >> 5;   // 32x8
    int bx = blockIdx.x * 32, by = blockIdx.y * 32;     // bx: n, by: k
#pragma unroll
    for (int yy = 0; yy < 4; ++yy)
        t[ty + yy * 8][tx] = W[(size_t)(by + ty + yy * 8) * 1024 + bx + tx];
    __syncthreads();
#pragma unroll
    for (int yy = 0; yy < 4; ++yy)
        O[(size_t)(bx + ty + yy * 8) * 1024 + by + tx] = (bf16_t)t[tx][ty + yy * 8];
}

// ---------------- RoPE tables: ctab/stab [2048][32] fp32 ----------------
__global__ __launch_bounds__(256) void rope_tab(float* __restrict__ ctab, float* __restrict__ stab) {
    int idx = blockIdx.x * 256 + threadIdx.x;   // 65536 = 2048*32
    int s = idx >> 5, i = idx & 31;
    float inv = 1.0f / powf(10000.0f, (float)i * (1.0f / 32.0f));
    float f = (float)s * inv;
    ctab[idx] = cosf(f);
    stab[idx] = sinf(f);
}

// ---------------- fused QKV projection GEMM (grid.z selects Q/K/V) ----------------
// Grid (64,8,3): blockIdx.x = M-row tile; linear%8 = x%8, so the 8 N-tiles of one M-row
// share an XCD's L2 (A row-tile fetched once per XCD).
// C[8192,1024] = A[8192,1024] x Wt[1024,1024]^T; epilogue:
//   z=0/1: RoPE + scale, bf16 store to [b,h,s,d]    (Q: scale=log2e/8, K: scale=1)
//   z=2:   bf16 store transposed to Vt[b,h,d,s]
__global__ __launch_bounds__(256) void gemm_qkv(const bf16_t* __restrict__ Xq, const bf16_t* __restrict__ Xk,
                                                const bf16_t* __restrict__ Xv, const bf16_t* __restrict__ Wqt,
                                                const bf16_t* __restrict__ Wkt, const bf16_t* __restrict__ Wvt,
                                                const float* __restrict__ bqp, const float* __restrict__ bkp,
                                                const float* __restrict__ bvp, bf16_t* __restrict__ Qo,
                                                bf16_t* __restrict__ Ko, bf16_t* __restrict__ Vo,
                                                const float* __restrict__ ctab, const float* __restrict__ stab) {
    constexpr int K = 1024;
    const int z = blockIdx.z;
    const bf16_t* A  = z == 0 ? Xq : z == 1 ? Xk : Xv;
    const bf16_t* Bt = z == 0 ? Wqt : z == 1 ? Wkt : Wvt;
    const float* bias = z == 0 ? bqp : z == 1 ? bkp : bvp;
    bf16_t* O = z == 0 ? Qo : z == 1 ? Ko : Vo;
    const float scale = z == 0 ? 0.18033688011112042f : 1.0f;   // log2(e)/8 folded into Q

    __shared__ alignas(16) bf16_t As[128 * 32];
    __shared__ alignas(16) bf16_t Bs[128 * 32];
    const int tid = threadIdx.x;
    const int w = tid >> 6, lane = tid & 63, c = lane & 15, qd = lane >> 4;
    const int wm = w >> 1, wn = w & 1;
    const int m0 = blockIdx.x * 128, n0 = blockIdx.y * 128;
    f32x4 acc[4][4] = {};
    for (int kt = 0; kt < K / 32; ++kt) {
#pragma unroll
        for (int l = 0; l < 2; ++l) {
            int e = (l * 256 + tid) * 8;
            int row = e >> 5, col = e & 31;
            gl_lds16(A + (size_t)(m0 + row) * K + kt * 32 + col, (char*)As + (size_t)e * 2);
            gl_lds16(Bt + (size_t)(n0 + row) * K + kt * 32 + col, (char*)Bs + (size_t)e * 2);
        }
        __syncthreads();
        bf16x8 af[4], bfr[4];
#pragma unroll
        for (int i = 0; i < 4; ++i) af[i] = *(const bf16x8*)&As[(wm * 64 + i * 16 + c) * 32 + qd * 8];
#pragma unroll
        for (int j = 0; j < 4; ++j) bfr[j] = *(const bf16x8*)&Bs[(wn * 64 + j * 16 + c) * 32 + qd * 8];
#pragma unroll
        for (int i = 0; i < 4; ++i)
#pragma unroll
            for (int j = 0; j < 4; ++j)
                acc[i][j] = __builtin_amdgcn_mfma_f32_16x16x32_bf16(af[i], bfr[j], acc[i][j], 0, 0, 0);
        __syncthreads();
    }
    const int mb = m0 + wm * 64;
    const int nb = n0 + wn * 64;   // head-aligned (64): nb>>6 = head
    const int h = nb >> 6;
    if (z == 2) {
        // V: store transposed Vt[b,h,d,s], packing 4 consecutive s per store
#pragma unroll
        for (int i = 0; i < 4; ++i) {
            int m = mb + i * 16 + qd * 4;     // 4 consecutive s at r=0..3, same b
            int b = m >> 11, s = m & 2047;
#pragma unroll
            for (int j = 0; j < 4; ++j) {
                int d = j * 16 + c;
                float bv = bias[nb + d];
                bf16x4v v4;
#pragma unroll
                for (int r = 0; r < 4; ++r) v4[r] = (bf16_t)(acc[i][j][r] + bv);
                *(bf16x4v*)(O + ((size_t)(b * 16 + h) * 64 + d) * 2048 + s) = v4;
            }
        }
    } else {
#pragma unroll
        for (int i = 0; i < 4; ++i)
#pragma unroll
            for (int jh = 0; jh < 2; ++jh) {
                int d1 = jh * 16 + c;                 // [0,32)
                float b1 = bias[nb + d1];
                float b2 = bias[nb + d1 + 32];
#pragma unroll
                for (int r = 0; r < 4; ++r) {
                    int m = mb + i * 16 + qd * 4 + r;
                    int b = m >> 11, s = m & 2047;
                    float v1 = acc[i][jh][r] + b1;
                    float v2 = acc[i][jh + 2][r] + b2;
                    float ct = ctab[s * 32 + d1];
                    float st = stab[s * 32 + d1];
                    size_t base = ((size_t)(b * 16 + h) * 2048 + s) * 64;
                    O[base + d1]      = (bf16_t)((v1 * ct - v2 * st) * scale);
                    O[base + d1 + 32] = (bf16_t)((v2 * ct + v1 * st) * scale);
                }
            }
    }
}

// ---------------- out-proj GEMM: fp32 store [m,n] + bias. Grid (64,8), x = M-tile ----------------
__global__ __launch_bounds__(256) void gemm_out(const bf16_t* __restrict__ A, const bf16_t* __restrict__ Bt,
                                                const float* __restrict__ bias, float* __restrict__ O) {
    constexpr int K = 1024, N = 1024;
    __shared__ alignas(16) bf16_t As[128 * 32];
    __shared__ alignas(16) bf16_t Bs[128 * 32];
    const int tid = threadIdx.x;
    const int w = tid >> 6, lane = tid & 63, c = lane & 15, qd = lane >> 4;
    const int wm = w >> 1, wn = w & 1;
    const int m0 = blockIdx.x * 128, n0 = blockIdx.y * 128;
    f32x4 acc[4][4] = {};
    for (int kt = 0; kt < K / 32; ++kt) {
#pragma unroll
        for (int l = 0; l < 2; ++l) {
            int e = (l * 256 + tid) * 8;
            int row = e >> 5, col = e & 31;
            gl_lds16(A + (size_t)(m0 + row) * K + kt * 32 + col, (char*)As + (size_t)e * 2);
            gl_lds16(Bt + (size_t)(n0 + row) * K + kt * 32 + col, (char*)Bs + (size_t)e * 2);
        }
        __syncthreads();
        bf16x8 af[4], bfr[4];
#pragma unroll
        for (int i = 0; i < 4; ++i) af[i] = *(const bf16x8*)&As[(wm * 64 + i * 16 + c) * 32 + qd * 8];
#pragma unroll
        for (int j = 0; j < 4; ++j) bfr[j] = *(const bf16x8*)&Bs[(wn * 64 + j * 16 + c) * 32 + qd * 8];
#pragma unroll
        for (int i = 0; i < 4; ++i)
#pragma unroll
            for (int j = 0; j < 4; ++j)
                acc[i][j] = __builtin_amdgcn_mfma_f32_16x16x32_bf16(af[i], bfr[j], acc[i][j], 0, 0, 0);
        __syncthreads();
    }
    const int mb = m0 + wm * 64, nb = n0 + wn * 64;
#pragma unroll
    for (int i = 0; i < 4; ++i)
#pragma unroll
        for (int j = 0; j < 4; ++j) {
            int n = nb + j * 16 + c;
            float bv = bias[n];
#pragma unroll
            for (int r = 0; r < 4; ++r) {
                int m = mb + i * 16 + qd * 4 + r;
                O[(size_t)m * N + n] = acc[i][j][r] + bv;
            }
        }
}

// ---------------- flash attention v5 ----------------
// Grid (64,16): blockIdx.x = bh; linear%8 = bh%8 so all 16 q-blocks of one bh land on the
// same XCD (K/V fetched from HBM once per XCD). 1024 blocks = 4/CU exactly, no tail.
// LDS 32KB: Q staged transiently into KV buf0's region, fragments hoisted to registers,
// then the region is recycled as double-buffered K/V.
// NO min-waves launch bound: (256,5) forced VGPR 76->48 and spilled accumulators to
// scratch (552MB writes, 2x slower). Natural 76 VGPR -> 4 blocks/CU, LDS allows 5.
// Swapped-QK (St = K.Q^T) -> P packed bf16 in-register; PV A-frags via 8 shfl + 4 sel.
// Q pre-scaled by log2(e)/8. Q,K: [b,h,s,64] bf16. Vt: [b,h,64,s] bf16.
// 16B-chunk XOR swizzle (chunk^((row>>1)&7)) keeps all b128 reads conflict-free.
__global__ __launch_bounds__(256) void attn(const bf16_t* __restrict__ Q, const bf16_t* __restrict__ K,
                                            const bf16_t* __restrict__ Vt, bf16_t* __restrict__ ctx) {
    constexpr int S = 2048;
    __shared__ alignas(16) char smem[32768];   // [buf][ K 8KB | V 8KB ] x2
    const int tid = threadIdx.x, w = tid >> 6, lane = tid & 63, c = lane & 15, qd = lane >> 4;
    const int bh = blockIdx.x, q0 = blockIdx.y * 128;
    const bf16_t* Qb = Q + (size_t)bh * S * 64 + (size_t)q0 * 64;
    const bf16_t* Kb = K + (size_t)bh * S * 64;
    const bf16_t* Vb = Vt + (size_t)bh * 64 * S;
    // ---- stage Q (16KB) into smem[0..16K), read fragments, then recycle the region ----
#pragma unroll
    for (int l = 0; l < 4; ++l) {
        int slot = l * 256 + tid;           // 16B slots
        int row = slot >> 3, ch = slot & 7;
        int sch = ch ^ ((row >> 1) & 7);
        gl_lds16(Qb + (size_t)row * 64 + sch * 8, smem + (size_t)slot * 16);
    }
    __syncthreads();
    const int rch = (c >> 1) & 7;                   // read-side swizzle mask
    bf16x8 qf[2][2];
    {
        const bf16_t* Qs = (const bf16_t*)smem;
#pragma unroll
        for (int kk = 0; kk < 2; ++kk) {
            const int ch = (4 * kk + qd) ^ rch;
#pragma unroll
            for (int i = 0; i < 2; ++i)
                qf[kk][i] = *(const bf16x8*)&Qs[(w * 32 + i * 16 + c) * 64 + ch * 8];
        }
    }
    __syncthreads();                                // all waves done reading Q
    auto stageKV = [&](int kt, int buf) {
        const int s0 = kt * 64;
        char* kbase = smem + buf * 16384;
        char* vbase = kbase + 8192;
#pragma unroll
        for (int l = 0; l < 2; ++l) {
            int slot = l * 256 + tid;
            int row = slot >> 3, ch = slot & 7;
            int sch = ch ^ ((row >> 1) & 7);
            gl_lds16(Kb + (size_t)(s0 + row) * 64 + sch * 8, kbase + (size_t)slot * 16);
            gl_lds16(Vb + (size_t)row * S + s0 + sch * 8, vbase + (size_t)slot * 16);
        }
    };
    stageKV(0, 0);
    __syncthreads();                                // tile 0 staged
    const int srcA = c + ((lane >> 4) & 1) * 32;    // (c, (qd&1)*2)
    const int srcB = srcA + 16;                     // (c, (qd&1)*2+1)
    const bool hisel = (qd >> 1) & 1;               // strip select: j = 2*kk + (qd>>1)
    f32x4 acc_o[2][4] = {};
    float ls[2] = {0.f, 0.f};
    const f32x4 Z = {0.f, 0.f, 0.f, 0.f};
    for (int kt = 0; kt < S / 64; ++kt) {
        const int cur = kt & 1;
        if (kt + 1 < S / 64) stageKV(kt + 1, cur ^ 1);
        const bf16_t* KsC = (const bf16_t*)(smem + cur * 16384);
        const bf16_t* VsC = (const bf16_t*)(smem + cur * 16384 + 8192);
        // St = K.Q^T : lane holds St[s=j*16+qd*4+r][q=i*16+c]
        f32x4 sc[4][2];
#pragma unroll
        for (int kk = 0; kk < 2; ++kk) {
            const int ch = (4 * kk + qd) ^ rch;
            bf16x8 kf[4];
#pragma unroll
            for (int j = 0; j < 4; ++j) kf[j] = *(const bf16x8*)&KsC[(j * 16 + c) * 64 + ch * 8];
#pragma unroll
            for (int j = 0; j < 4; ++j)
#pragma unroll
                for (int i = 0; i < 2; ++i)
                    sc[j][i] = __builtin_amdgcn_mfma_f32_16x16x32_bf16(kf[j], qf[kk][i],
                                                                       kk == 0 ? Z : sc[j][i], 0, 0, 0);
        }
        // p = 2^sc; row-sum per q (lane's q = i*16+c); pack pairs (s, s+1) -> u32
        uint32_t pku[4][2][2];
#pragma unroll
        for (int j = 0; j < 4; ++j)
#pragma unroll
            for (int i = 0; i < 2; ++i) {
                float p0 = fexp2(sc[j][i][0]), p1 = fexp2(sc[j][i][1]);
                float p2 = fexp2(sc[j][i][2]), p3 = fexp2(sc[j][i][3]);
                ls[i] += (p0 + p1) + (p2 + p3);
                pku[j][i][0] = pkbf16(p0, p1);
                pku[j][i][1] = pkbf16(p2, p3);
            }
        // O += P.V : A-frag built cross-lane, B-frag from Vts rows (d-major)
#pragma unroll
        for (int kk = 0; kk < 2; ++kk) {
            const int ch = (4 * kk + qd) ^ rch;
            bf16x8 vf[4];
#pragma unroll
            for (int j = 0; j < 4; ++j) vf[j] = *(const bf16x8*)&VsC[(j * 16 + c) * 64 + ch * 8];
#pragma unroll
            for (int i = 0; i < 2; ++i) {
                uint32_t a0, a1, a2, a3;
                {
                    uint32_t lo = __shfl(pku[2 * kk][i][0], srcA);
                    uint32_t hi = __shfl(pku[2 * kk + 1][i][0], srcA);
                    a0 = hisel ? hi : lo;
                    lo = __shfl(pku[2 * kk][i][1], srcA);
                    hi = __shfl(pku[2 * kk + 1][i][1], srcA);
                    a1 = hisel ? hi : lo;
                    lo = __shfl(pku[2 * kk][i][0], srcB);
                    hi = __shfl(pku[2 * kk + 1][i][0], srcB);
                    a2 = hisel ? hi : lo;
                    lo = __shfl(pku[2 * kk][i][1], srcB);
                    hi = __shfl(pku[2 * kk + 1][i][1], srcB);
                    a3 = hisel ? hi : lo;
                }
                u32x4 av = {a0, a1, a2, a3};
                bf16x8 af = __builtin_bit_cast(bf16x8, av);
#pragma unroll
                for (int j = 0; j < 4; ++j)
                    acc_o[i][j] = __builtin_amdgcn_mfma_f32_16x16x32_bf16(af, vf[j], acc_o[i][j], 0, 0, 0);
            }
        }
        __syncthreads();
    }
    // complete l over qd groups, redistribute inverse to C-layout rows
    float linv[2][4];
#pragma unroll
    for (int i = 0; i < 2; ++i) {
        float v = ls[i];
        v += __shfl_xor(v, 16);
        v += __shfl_xor(v, 32);
        float vinv = 1.0f / v;
#pragma unroll
        for (int r = 0; r < 4; ++r)
            linv[i][r] = __shfl(vinv, qd * 20 + r);   // lane (qd*16 + qd*4 + r): holds l[q=i*16+qd*4+r]
    }
    const int b = bh >> 4, h = bh & 15;
#pragma unroll
    for (int i = 0; i < 2; ++i)
#pragma unroll
        for (int j = 0; j < 4; ++j)
#pragma unroll
            for (int r = 0; r < 4; ++r) {
                int qrow = q0 + w * 32 + i * 16 + qd * 4 + r;
                float o = acc_o[i][j][r] * linv[i][r];
                ctx[((size_t)(b * 2048 + qrow)) * 1024 + (size_t)h * 64 + j * 16 + c] = (bf16_t)o;
            }
}

extern "C" void kernel_launch(void* const* d_in, const int* in_sizes, int n_in,
                              void* d_out, int out_size, void* d_ws, size_t ws_size,
                              hipStream_t stream) {
    (void)in_sizes; (void)n_in; (void)out_size; (void)ws_size;
    const float* query = (const float*)d_in[0];
    const float* key   = (const float*)d_in[1];
    const float* value = (const float*)d_in[2];
    const float* Wq = (const float*)d_in[3];
    const float* bq = (const float*)d_in[4];
    const float* Wk = (const float*)d_in[5];
    const float* bk = (const float*)d_in[6];
    const float* Wv = (const float*)d_in[7];
    const float* bv = (const float*)d_in[8];
    const float* Wo = (const float*)d_in[9];
    const float* bo = (const float*)d_in[10];

    const size_t SZ = (size_t)8192 * 1024;
    bf16_t* Xq = (bf16_t*)d_ws;
    bf16_t* Xk = Xq + SZ;
    bf16_t* Xv = Xk + SZ;
    bf16_t* Qb = Xv + SZ;
    bf16_t* Kb = Qb + SZ;
    bf16_t* Vtb = Kb + SZ;          // own buffer: fused QKV gemm runs Q/K/V concurrently
    bf16_t* Wqt = Vtb + SZ;
    bf16_t* Wkt = Wqt + 1024 * 1024;
    bf16_t* Wvt = Wkt + 1024 * 1024;
    bf16_t* Wot = Wvt + 1024 * 1024;
    float* ctab = (float*)(Wot + 1024 * 1024);
    float* stab = ctab + 2048 * 32;
    bf16_t* CT = Xq;                // alias: Xq dead after projection GEMM

    castk<<<dim3(8192, 3), 256, 0, stream>>>(query, key, value, Xq, Xk, Xv);
    wtrans<<<dim3(32, 32, 4), 256, 0, stream>>>(Wq, Wk, Wv, Wo, Wqt, Wkt, Wvt, Wot);
    rope_tab<<<256, 256, 0, stream>>>(ctab, stab);
    gemm_qkv<<<dim3(64, 8, 3), 256, 0, stream>>>(Xq, Xk, Xv, Wqt, Wkt, Wvt, bq, bk, bv,
                                                 Qb, Kb, Vtb, ctab, stab);
    attn<<<dim3(64, 16), 256, 0, stream>>>(Qb, Kb, Vtb, CT);
    gemm_out<<<dim3(64, 8), 256, 0, stream>>>(CT, Wot, bo, (float*)d_out);
}

// Round 6
// 363.242 us; speedup vs baseline: 1.3709x; 1.0794x over previous
//
#include <hip/hip_runtime.h>
#include <hip/hip_bf16.h>
#include <cstdint>
#include <cstddef>

typedef __bf16 bf16_t;
typedef __bf16 bf16x8 __attribute__((ext_vector_type(8)));
typedef __bf16 bf16x4v __attribute__((ext_vector_type(4)));
typedef __bf16 bf16x2v __attribute__((ext_vector_type(2)));
typedef float f32x4 __attribute__((ext_vector_type(4)));
typedef float f32x16 __attribute__((ext_vector_type(16)));
typedef uint32_t u32x4 __attribute__((ext_vector_type(4)));

#define DEVI static __device__ __forceinline__

// async global->LDS, 16B per lane. LDS dest must be wave-uniform base + lane*16.
DEVI void gl_lds16(const void* g, void* l) {
    __builtin_amdgcn_global_load_lds((const __attribute__((address_space(1))) void*)g,
                                     (__attribute__((address_space(3))) void*)l, 16, 0, 0);
}

DEVI float fexp2(float x) {
#if __has_builtin(__builtin_amdgcn_exp2f)
    return __builtin_amdgcn_exp2f(x);
#else
    return __expf(x * 0.6931471805599453f);
#endif
}

DEVI uint32_t pkbf16(float a, float b) {
    bf16x2v t;
    t[0] = (bf16_t)a;
    t[1] = (bf16_t)b;
    return __builtin_bit_cast(uint32_t, t);
}

// ---------------- cast fp32 -> bf16 (3 tensors in one launch) ----------------
__global__ __launch_bounds__(256) void castk(const float* __restrict__ i0, const float* __restrict__ i1,
                                             const float* __restrict__ i2, bf16_t* __restrict__ o0,
                                             bf16_t* __restrict__ o1, bf16_t* __restrict__ o2) {
    const float* in = blockIdx.y == 0 ? i0 : blockIdx.y == 1 ? i1 : i2;
    bf16_t* out = blockIdx.y == 0 ? o0 : blockIdx.y == 1 ? o1 : o2;
    size_t i = ((size_t)blockIdx.x * 256 + threadIdx.x) * 4;
    float4 v = *(const float4*)(in + i);
    bf16x4v o;
    o[0] = (bf16_t)v.x; o[1] = (bf16_t)v.y; o[2] = (bf16_t)v.z; o[3] = (bf16_t)v.w;
    *(bf16x4v*)(out + i) = o;
}

// ---------------- transpose+cast weight 1024x1024: Wt[n][k] = W[k][n] ----------------
__global__ __launch_bounds__(256) void wtrans(const float* __restrict__ W0, const float* __restrict__ W1,
                                              const float* __restrict__ W2, const float* __restrict__ W3,
                                              bf16_t* __restrict__ O0, bf16_t* __restrict__ O1,
                                              bf16_t* __restrict__ O2, bf16_t* __restrict__ O3) {
    const float* W; bf16_t* O;
    switch (blockIdx.z) {
        case 0: W = W0; O = O0; break;
        case 1: W = W1; O = O1; break;
        case 2: W = W2; O = O2; break;
        default: W = W3; O = O3; break;
    }
    __shared__ float t[32][33];
    int tx = threadIdx.x & 31, ty = threadIdx.x >> 5;   // 32x8
    int bx = blockIdx.x * 32, by = blockIdx.y * 32;     // bx: n, by: k
#pragma unroll
    for (int yy = 0; yy < 4; ++yy)
        t[ty + yy * 8][tx] = W[(size_t)(by + ty + yy * 8) * 1024 + bx + tx];
    __syncthreads();
#pragma unroll
    for (int yy = 0; yy < 4; ++yy)
        O[(size_t)(bx + ty + yy * 8) * 1024 + by + tx] = (bf16_t)t[tx][ty + yy * 8];
}

// ---------------- RoPE tables: ctab/stab [2048][32] fp32 ----------------
__global__ __launch_bounds__(256) void rope_tab(float* __restrict__ ctab, float* __restrict__ stab) {
    int idx = blockIdx.x * 256 + threadIdx.x;   // 65536 = 2048*32
    int s = idx >> 5, i = idx & 31;
    float inv = 1.0f / powf(10000.0f, (float)i * (1.0f / 32.0f));
    float f = (float)s * inv;
    ctab[idx] = cosf(f);
    stab[idx] = sinf(f);
}

// ---------------- fused QKV projection GEMM (grid.z selects Q/K/V) ----------------
// Grid (64,8,3): blockIdx.x = M-row tile; linear%8 = x%8, so the 8 N-tiles of one M-row
// share an XCD's L2 (A row-tile fetched once per XCD).
__global__ __launch_bounds__(256) void gemm_qkv(const bf16_t* __restrict__ Xq, const bf16_t* __restrict__ Xk,
                                                const bf16_t* __restrict__ Xv, const bf16_t* __restrict__ Wqt,
                                                const bf16_t* __restrict__ Wkt, const bf16_t* __restrict__ Wvt,
                                                const float* __restrict__ bqp, const float* __restrict__ bkp,
                                                const float* __restrict__ bvp, bf16_t* __restrict__ Qo,
                                                bf16_t* __restrict__ Ko, bf16_t* __restrict__ Vo,
                                                const float* __restrict__ ctab, const float* __restrict__ stab) {
    constexpr int K = 1024;
    const int z = blockIdx.z;
    const bf16_t* A  = z == 0 ? Xq : z == 1 ? Xk : Xv;
    const bf16_t* Bt = z == 0 ? Wqt : z == 1 ? Wkt : Wvt;
    const float* bias = z == 0 ? bqp : z == 1 ? bkp : bvp;
    bf16_t* O = z == 0 ? Qo : z == 1 ? Ko : Vo;
    const float scale = z == 0 ? 0.18033688011112042f : 1.0f;   // log2(e)/8 folded into Q

    __shared__ alignas(16) bf16_t As[128 * 32];
    __shared__ alignas(16) bf16_t Bs[128 * 32];
    const int tid = threadIdx.x;
    const int w = tid >> 6, lane = tid & 63, c = lane & 15, qd = lane >> 4;
    const int wm = w >> 1, wn = w & 1;
    const int m0 = blockIdx.x * 128, n0 = blockIdx.y * 128;
    f32x4 acc[4][4] = {};
    for (int kt = 0; kt < K / 32; ++kt) {
#pragma unroll
        for (int l = 0; l < 2; ++l) {
            int e = (l * 256 + tid) * 8;
            int row = e >> 5, col = e & 31;
            gl_lds16(A + (size_t)(m0 + row) * K + kt * 32 + col, (char*)As + (size_t)e * 2);
            gl_lds16(Bt + (size_t)(n0 + row) * K + kt * 32 + col, (char*)Bs + (size_t)e * 2);
        }
        __syncthreads();
        bf16x8 af[4], bfr[4];
#pragma unroll
        for (int i = 0; i < 4; ++i) af[i] = *(const bf16x8*)&As[(wm * 64 + i * 16 + c) * 32 + qd * 8];
#pragma unroll
        for (int j = 0; j < 4; ++j) bfr[j] = *(const bf16x8*)&Bs[(wn * 64 + j * 16 + c) * 32 + qd * 8];
#pragma unroll
        for (int i = 0; i < 4; ++i)
#pragma unroll
            for (int j = 0; j < 4; ++j)
                acc[i][j] = __builtin_amdgcn_mfma_f32_16x16x32_bf16(af[i], bfr[j], acc[i][j], 0, 0, 0);
        __syncthreads();
    }
    const int mb = m0 + wm * 64;
    const int nb = n0 + wn * 64;   // head-aligned (64): nb>>6 = head
    const int h = nb >> 6;
    if (z == 2) {
        // V: store transposed Vt[b,h,d,s], packing 4 consecutive s per store
#pragma unroll
        for (int i = 0; i < 4; ++i) {
            int m = mb + i * 16 + qd * 4;     // 4 consecutive s at r=0..3, same b
            int b = m >> 11, s = m & 2047;
#pragma unroll
            for (int j = 0; j < 4; ++j) {
                int d = j * 16 + c;
                float bv = bias[nb + d];
                bf16x4v v4;
#pragma unroll
                for (int r = 0; r < 4; ++r) v4[r] = (bf16_t)(acc[i][j][r] + bv);
                *(bf16x4v*)(O + ((size_t)(b * 16 + h) * 64 + d) * 2048 + s) = v4;
            }
        }
    } else {
#pragma unroll
        for (int i = 0; i < 4; ++i)
#pragma unroll
            for (int jh = 0; jh < 2; ++jh) {
                int d1 = jh * 16 + c;                 // [0,32)
                float b1 = bias[nb + d1];
                float b2 = bias[nb + d1 + 32];
#pragma unroll
                for (int r = 0; r < 4; ++r) {
                    int m = mb + i * 16 + qd * 4 + r;
                    int b = m >> 11, s = m & 2047;
                    float v1 = acc[i][jh][r] + b1;
                    float v2 = acc[i][jh + 2][r] + b2;
                    float ct = ctab[s * 32 + d1];
                    float st = stab[s * 32 + d1];
                    size_t base = ((size_t)(b * 16 + h) * 2048 + s) * 64;
                    O[base + d1]      = (bf16_t)((v1 * ct - v2 * st) * scale);
                    O[base + d1 + 32] = (bf16_t)((v2 * ct + v1 * st) * scale);
                }
            }
    }
}

// ---------------- out-proj GEMM: fp32 store [m,n] + bias. Grid (64,8), x = M-tile ----------------
__global__ __launch_bounds__(256) void gemm_out(const bf16_t* __restrict__ A, const bf16_t* __restrict__ Bt,
                                                const float* __restrict__ bias, float* __restrict__ O) {
    constexpr int K = 1024, N = 1024;
    __shared__ alignas(16) bf16_t As[128 * 32];
    __shared__ alignas(16) bf16_t Bs[128 * 32];
    const int tid = threadIdx.x;
    const int w = tid >> 6, lane = tid & 63, c = lane & 15, qd = lane >> 4;
    const int wm = w >> 1, wn = w & 1;
    const int m0 = blockIdx.x * 128, n0 = blockIdx.y * 128;
    f32x4 acc[4][4] = {};
    for (int kt = 0; kt < K / 32; ++kt) {
#pragma unroll
        for (int l = 0; l < 2; ++l) {
            int e = (l * 256 + tid) * 8;
            int row = e >> 5, col = e & 31;
            gl_lds16(A + (size_t)(m0 + row) * K + kt * 32 + col, (char*)As + (size_t)e * 2);
            gl_lds16(Bt + (size_t)(n0 + row) * K + kt * 32 + col, (char*)Bs + (size_t)e * 2);
        }
        __syncthreads();
        bf16x8 af[4], bfr[4];
#pragma unroll
        for (int i = 0; i < 4; ++i) af[i] = *(const bf16x8*)&As[(wm * 64 + i * 16 + c) * 32 + qd * 8];
#pragma unroll
        for (int j = 0; j < 4; ++j) bfr[j] = *(const bf16x8*)&Bs[(wn * 64 + j * 16 + c) * 32 + qd * 8];
#pragma unroll
        for (int i = 0; i < 4; ++i)
#pragma unroll
            for (int j = 0; j < 4; ++j)
                acc[i][j] = __builtin_amdgcn_mfma_f32_16x16x32_bf16(af[i], bfr[j], acc[i][j], 0, 0, 0);
        __syncthreads();
    }
    const int mb = m0 + wm * 64, nb = n0 + wn * 64;
#pragma unroll
    for (int i = 0; i < 4; ++i)
#pragma unroll
        for (int j = 0; j < 4; ++j) {
            int n = nb + j * 16 + c;
            float bv = bias[n];
#pragma unroll
            for (int r = 0; r < 4; ++r) {
                int m = mb + i * 16 + qd * 4 + r;
                O[(size_t)m * N + n] = acc[i][j][r] + bv;
            }
        }
}

// ---------------- flash attention v6: 32x32x16 MFMA, 64 q/wave ----------------
// Grid (64,8): x = bh (linear%8 = bh%8 -> all q-blocks of a bh on one XCD). 512 blocks
// = 2/CU exact. Block: 4 waves x 64 q = 256 q. LDS 32KB: Q tile (256x64) staged
// transiently, frags hoisted, region recycled as double-buffered K/V (16KB each).
// Swapped QK: St[s][q] = K.Q^T via mfma_32x32x16 (A=K, B=Q). In 32x32 C-layout
// (col=lane&31, row=(reg&3)+8*(reg>>2)+4*(lane>>5)) the St->PV-A transform needs only
// a lane^32 half-exchange: per A-frag 2 shfl_xor(32) + 6 cndmask (4x fewer LDS
// cross-lane ops than the 16x16 bpermute scheme). V[d][s] serves the PV B-operand
// directly as b128 reads. Row-sums l via MFMA with an all-ones B-frag (acc_l rows
// align with acc_o rows -> no end shuffles).
// Q pre-scaled by log2(e)/8. Q,K: [b,h,s,64] bf16. Vt: [b,h,64,s] bf16.
// 16B-chunk XOR swizzle (chunk^((row>>1)&7)) keeps b128 reads conflict-free.
__global__ __launch_bounds__(256) void attn(const bf16_t* __restrict__ Q, const bf16_t* __restrict__ K,
                                            const bf16_t* __restrict__ Vt, bf16_t* __restrict__ ctx) {
    constexpr int S = 2048;
    __shared__ alignas(16) char smem[32768];   // Q stage 32KB -> [buf][K 8KB | V 8KB] x2
    const int tid = threadIdx.x, w = tid >> 6, lane = tid & 63;
    const int lo5 = lane & 31, hi = lane >> 5;
    const int rm = (lo5 >> 1) & 7;              // read-side swizzle mask (row mod 16)/2
    const int bh = blockIdx.x, q0 = blockIdx.y * 256;
    const bf16_t* Qb = Q + (size_t)bh * S * 64 + (size_t)q0 * 64;
    const bf16_t* Kb = K + (size_t)bh * S * 64;
    const bf16_t* Vb = Vt + (size_t)bh * 64 * S;
    // ---- stage Q (256x64 = 32KB), read B-frags, recycle region ----
#pragma unroll
    for (int l = 0; l < 8; ++l) {
        int slot = l * 256 + tid;               // 16B slots
        int row = slot >> 3, ch = slot & 7;
        int sch = ch ^ ((row >> 1) & 7);
        gl_lds16(Qb + (size_t)row * 64 + sch * 8, smem + (size_t)slot * 16);
    }
    __syncthreads();
    bf16x8 qf[4][2];                            // [kc][qb]: B[n=q=w*64+qb*32+lo5][k=d=kc*16+hi*8+j]
    {
        const bf16_t* Qs = (const bf16_t*)smem;
#pragma unroll
        for (int kc = 0; kc < 4; ++kc)
#pragma unroll
            for (int qb = 0; qb < 2; ++qb)
                qf[kc][qb] = *(const bf16x8*)&Qs[(size_t)(w * 64 + qb * 32 + lo5) * 64 + ((kc * 2 + hi) ^ rm) * 8];
    }
    __syncthreads();                            // all waves done reading Q
    auto stageKV = [&](int kt, int buf) {
        const int s0 = kt * 64;
        char* kbase = smem + buf * 16384;
        char* vbase = kbase + 8192;
#pragma unroll
        for (int l = 0; l < 2; ++l) {
            int slot = l * 256 + tid;
            int row = slot >> 3, ch = slot & 7;
            int sch = ch ^ ((row >> 1) & 7);
            gl_lds16(Kb + (size_t)(s0 + row) * 64 + sch * 8, kbase + (size_t)slot * 16);
            gl_lds16(Vb + (size_t)row * S + s0 + sch * 8, vbase + (size_t)slot * 16);
        }
    };
    stageKV(0, 0);
    f32x16 acc_o[2][2] = {};                    // [qb][db]
    f32x16 acc_l[2] = {};                       // [qb] row-sums (all cols equal)
    const f32x16 Z16 = {};
    bf16x8 ones;
    {
        u32x4 ov = {0x3F803F80u, 0x3F803F80u, 0x3F803F80u, 0x3F803F80u};
        ones = __builtin_bit_cast(bf16x8, ov);
    }
    __syncthreads();                            // tile 0 staged
    for (int kt = 0; kt < S / 64; ++kt) {
        const int cur = kt & 1;
        if (kt + 1 < S / 64) stageKV(kt + 1, cur ^ 1);
        const bf16_t* KsC = (const bf16_t*)(smem + cur * 16384);
        const bf16_t* VsC = (const bf16_t*)(smem + cur * 16384 + 8192);
        // St[s][q]: A=K[m=s=sb*32+lo5][k=d], B=Q
        f32x16 st[2][2];                        // [sb][qb]
#pragma unroll
        for (int kc = 0; kc < 4; ++kc) {
            bf16x8 kf[2];
#pragma unroll
            for (int sb = 0; sb < 2; ++sb)
                kf[sb] = *(const bf16x8*)&KsC[(size_t)(sb * 32 + lo5) * 64 + ((kc * 2 + hi) ^ rm) * 8];
#pragma unroll
            for (int sb = 0; sb < 2; ++sb)
#pragma unroll
                for (int qb = 0; qb < 2; ++qb)
                    st[sb][qb] = __builtin_amdgcn_mfma_f32_32x32x16_bf16(kf[sb], qf[kc][qb],
                                                                         kc == 0 ? Z16 : st[sb][qb], 0, 0, 0);
        }
        // p = 2^st, pack s-pairs: pku[sb][qb][u] covers s = sb*32 + 8*(u>>1) + 4*hi + 2*(u&1) + {0,1}
        uint32_t pku[2][2][8];
#pragma unroll
        for (int sb = 0; sb < 2; ++sb)
#pragma unroll
            for (int qb = 0; qb < 2; ++qb)
#pragma unroll
                for (int u = 0; u < 8; ++u)
                    pku[sb][qb][u] = pkbf16(fexp2(st[sb][qb][2 * u]), fexp2(st[sb][qb][2 * u + 1]));
        // PV: A = P[m=q][k=s chunk skc], B = V[n=d][k=s]; plus l via ones B-frag
#pragma unroll
        for (int skc = 0; skc < 4; ++skc) {
            bf16x8 vf[2];
#pragma unroll
            for (int db = 0; db < 2; ++db)
                vf[db] = *(const bf16x8*)&VsC[(size_t)(db * 32 + lo5) * 64 + ((skc * 2 + hi) ^ rm) * 8];
            const int sb = skc >> 1, b = (skc & 1) * 4;
#pragma unroll
            for (int qb = 0; qb < 2; ++qb) {
                uint32_t p0 = pku[sb][qb][b + 0], p1 = pku[sb][qb][b + 1];
                uint32_t p2 = pku[sb][qb][b + 2], p3 = pku[sb][qb][b + 3];
                uint32_t send0 = hi ? p0 : p2;
                uint32_t send1 = hi ? p1 : p3;
                uint32_t recv0 = __shfl_xor(send0, 32);
                uint32_t recv1 = __shfl_xor(send1, 32);
                u32x4 av = {hi ? recv0 : p0, hi ? recv1 : p1,
                            hi ? p2 : recv0, hi ? p3 : recv1};
                bf16x8 af = __builtin_bit_cast(bf16x8, av);
                acc_l[qb] = __builtin_amdgcn_mfma_f32_32x32x16_bf16(af, ones, acc_l[qb], 0, 0, 0);
#pragma unroll
                for (int db = 0; db < 2; ++db)
                    acc_o[qb][db] = __builtin_amdgcn_mfma_f32_32x32x16_bf16(af, vf[db], acc_o[qb][db], 0, 0, 0);
            }
        }
        __syncthreads();
    }
    // epilogue: o = acc_o / acc_l (rows aligned); C row = (reg&3)+8*(reg>>2)+4*hi, col = lo5
    const int b = bh >> 4, h = bh & 15;
#pragma unroll
    for (int qb = 0; qb < 2; ++qb) {
        float linv[16];
#pragma unroll
        for (int r = 0; r < 16; ++r) linv[r] = 1.0f / acc_l[qb][r];
#pragma unroll
        for (int db = 0; db < 2; ++db)
#pragma unroll
            for (int r = 0; r < 16; ++r) {
                int qrow = q0 + w * 64 + qb * 32 + (r & 3) + 8 * (r >> 2) + 4 * hi;
                int d = db * 32 + lo5;
                float o = acc_o[qb][db][r] * linv[r];
                ctx[((size_t)(b * 2048 + qrow)) * 1024 + (size_t)h * 64 + d] = (bf16_t)o;
            }
    }
}

extern "C" void kernel_launch(void* const* d_in, const int* in_sizes, int n_in,
                              void* d_out, int out_size, void* d_ws, size_t ws_size,
                              hipStream_t stream) {
    (void)in_sizes; (void)n_in; (void)out_size; (void)ws_size;
    const float* query = (const float*)d_in[0];
    const float* key   = (const float*)d_in[1];
    const float* value = (const float*)d_in[2];
    const float* Wq = (const float*)d_in[3];
    const float* bq = (const float*)d_in[4];
    const float* Wk = (const float*)d_in[5];
    const float* bk = (const float*)d_in[6];
    const float* Wv = (const float*)d_in[7];
    const float* bv = (const float*)d_in[8];
    const float* Wo = (const float*)d_in[9];
    const float* bo = (const float*)d_in[10];

    const size_t SZ = (size_t)8192 * 1024;
    bf16_t* Xq = (bf16_t*)d_ws;
    bf16_t* Xk = Xq + SZ;
    bf16_t* Xv = Xk + SZ;
    bf16_t* Qb = Xv + SZ;
    bf16_t* Kb = Qb + SZ;
    bf16_t* Vtb = Kb + SZ;
    bf16_t* Wqt = Vtb + SZ;
    bf16_t* Wkt = Wqt + 1024 * 1024;
    bf16_t* Wvt = Wkt + 1024 * 1024;
    bf16_t* Wot = Wvt + 1024 * 1024;
    float* ctab = (float*)(Wot + 1024 * 1024);
    float* stab = ctab + 2048 * 32;
    bf16_t* CT = Xq;                // alias: Xq dead after projection GEMM

    castk<<<dim3(8192, 3), 256, 0, stream>>>(query, key, value, Xq, Xk, Xv);
    wtrans<<<dim3(32, 32, 4), 256, 0, stream>>>(Wq, Wk, Wv, Wo, Wqt, Wkt, Wvt, Wot);
    rope_tab<<<256, 256, 0, stream>>>(ctab, stab);
    gemm_qkv<<<dim3(64, 8, 3), 256, 0, stream>>>(Xq, Xk, Xv, Wqt, Wkt, Wvt, bq, bk, bv,
                                                 Qb, Kb, Vtb, ctab, stab);
    attn<<<dim3(64, 8), 256, 0, stream>>>(Qb, Kb, Vtb, CT);
    gemm_out<<<dim3(64, 8), 256, 0, stream>>>(CT, Wot, bo, (float*)d_out);
}